// Round 6
// baseline (301.190 us; speedup 1.0000x reference)
//
#include <hip/hip_runtime.h>
#include <math.h>

// ---------------------------------------------------------------------------
// Fully fused MRA, single-pass stencil: one block = one plane, 512 threads =
// 8 waves, each wave owns an 8-row strip of the 64x64 pooled tile. ONE
// barrier. LDS = T(64x80) = 20480 B only (gateL eliminated via shuffles).
//
// Phase A (per-wave, barrier-free): maxpool3x3(s1,p1) + blurpool([1,3,3,1]^2
//   /64, s3, reflect(1,2)) directly from global x with a rolling 6x6 register
//   window. Row/col clamp == replicate (exact for max windows); blur reflect
//   at i=0/j=0 via 1-op selects. Writes cols 6..69 of own T strip; border
//   cols stay zero = stencil zero-pad.
// [barrier]
// Phase B+C (single merged pass): ALL FOUR stencils accumulate into ONE
//   rotating 13-deep register file over one 20-iteration t-loop (they share
//   the same 13-wide LDS window w_[d] = T[t*80+j+d]):
//     h1: racc[(tt+11-p)%13] += Wh1[p][*] . w_[5..7]
//     h2: racc[(tt+11-p)%13] += Wh2[p][*] . w_[10-p..12-p]
//     w1: racc[(tt+7-p)%13]  += Wv1[p][q] * w_[q+1]
//     w2: racc[(tt+2-p+q)%13]+= Wv2[p][q] * w_[q+1]
//   All taps for output i arrive by t = i+6 = emit time. At tt>=12: BN +
//   sigmoid -> per-lane gate g (lane = gate column); nearest-upsample gather
//   via 6 __shfl (gate row is exactly 1 value/lane); stream out rows
//   3i..3i+2 (x loads L3-hot from phase A). Stores spread across the pass.
// ---------------------------------------------------------------------------
__global__ __launch_bounds__(512, 8) void mra_fused(
    const float* __restrict__ x,
    const float* __restrict__ wh1g, const float* __restrict__ wv1g,
    const float* __restrict__ wh2g, const float* __restrict__ wv2g,
    const float* __restrict__ gamma, const float* __restrict__ beta,
    const float* __restrict__ mean, const float* __restrict__ var,
    float* __restrict__ out) {
    const int plane = blockIdx.x;          // 0..1023
    const int c = plane & 63;
    __shared__ float T[64 * 80];           // pooled tile, cols 6..69 live

    const int j = threadIdx.x & 63;        // lane = column
    const int il = threadIdx.x >> 6;       // wave id 0..7
    const int ib = il * 8;                 // strip base row

    // zero own 8-row strip of T (wave-local)
    {
        float4 z4 = make_float4(0.f, 0.f, 0.f, 0.f);
        float4* t4 = (float4*)(T + ib * 80);   // 8*80 floats = 160 float4
#pragma unroll
        for (int u = 0; u < 3; ++u) {
            int idx = u * 64 + j;
            if (idx < 160) t4[idx] = z4;
        }
    }

    const float* xp = x + (size_t)plane * 36864;

    // ---- Phase A: per-wave pooling into own strip of T ----
    {
        int colk[6];
#pragma unroll
        for (int k = 0; k < 6; ++k)
            colk[k] = min(max(3 * j - 2 + k, 0), 191);

        float rw[6][6];
#pragma unroll
        for (int s = 0; s < 6; ++s) {
            const float* rp = xp + (size_t)min(max(3 * ib - 2 + s, 0), 191) * 192;
#pragma unroll
            for (int k = 0; k < 6; ++k) rw[s][k] = rp[colk[k]];
        }

#define POOL_EMIT(I, S0, S1, S2, S3, S4, S5)                              \
        {                                                                 \
            float cbv[4];                                                 \
            {                                                             \
                float vmu[4][6];                                          \
                _Pragma("unroll") for (int k = 0; k < 6; ++k) {           \
                    float p0 = rw[S0][k], p1 = rw[S1][k], p2 = rw[S2][k]; \
                    float p3 = rw[S3][k], p4 = rw[S4][k], p5 = rw[S5][k]; \
                    float q1 = fmaxf(p1, p2), q2 = fmaxf(p2, p3);         \
                    float q3 = fmaxf(p3, p4), q4 = fmaxf(p4, p5);         \
                    vmu[0][k] = fmaxf(p0, q1);                            \
                    vmu[1][k] = fmaxf(p1, q2);                            \
                    vmu[2][k] = fmaxf(p2, q3);                            \
                    vmu[3][k] = fmaxf(p3, q4);                            \
                }                                                         \
                _Pragma("unroll") for (int u = 0; u < 4; ++u) {           \
                    float g1 = fmaxf(vmu[u][1], vmu[u][2]);               \
                    float g2 = fmaxf(vmu[u][2], vmu[u][3]);               \
                    float g3 = fmaxf(vmu[u][3], vmu[u][4]);               \
                    float g4 = fmaxf(vmu[u][4], vmu[u][5]);               \
                    float h0 = fmaxf(vmu[u][0], g1);                      \
                    float h1 = fmaxf(vmu[u][1], g2);                      \
                    float h2 = fmaxf(vmu[u][2], g3);                      \
                    float h3 = fmaxf(vmu[u][3], g4);                      \
                    float ha = (j == 0) ? h2 : h0;   /* col reflect */    \
                    cbv[u] = ha + 3.f * h1 + 3.f * h2 + h3;               \
                }                                                         \
            }                                                             \
            float c0 = ((I) == 0) ? cbv[2] : cbv[0]; /* row reflect */    \
            float accv = c0 + 3.f * cbv[1] + 3.f * cbv[2] + cbv[3];       \
            T[(I) * 80 + 6 + j] = accv * (1.f / 64.f);                    \
        }

#define LOAD3(BR, S0, S1, S2)                                             \
        {                                                                 \
            const float* rp0 = xp + (size_t)min((BR), 191) * 192;         \
            const float* rp1 = xp + (size_t)min((BR) + 1, 191) * 192;     \
            const float* rp2 = xp + (size_t)min((BR) + 2, 191) * 192;     \
            _Pragma("unroll") for (int k = 0; k < 6; ++k) {               \
                rw[S0][k] = rp0[colk[k]];                                 \
                rw[S1][k] = rp1[colk[k]];                                 \
                rw[S2][k] = rp2[colk[k]];                                 \
            }                                                             \
        }

#pragma unroll 1
        for (int ii = 0; ii < 8; ii += 2) {
            const int i = ib + ii;
            POOL_EMIT(i, 0, 1, 2, 3, 4, 5);
            LOAD3(3 * i + 4, 0, 1, 2);
            POOL_EMIT(i + 1, 3, 4, 5, 0, 1, 2);
            if (ii < 6) LOAD3(3 * i + 7, 3, 4, 5);
        }
#undef POOL_EMIT
#undef LOAD3
    }
    __syncthreads();   // the ONLY barrier: T complete incl. halo strips

    // ---- Phase B+C: merged stencil + BN/sigmoid + streamed output ----
    const float inv = gamma[c] * rsqrtf(var[c] + 1e-5f);
    const float bias = beta[c] - mean[c] * inv;
    const int t0 = ib - 6;

    float Wh1[33], Wh2[33], Wv1[33], Wv2[33];
#pragma unroll
    for (int k = 0; k < 33; ++k) {
        Wh1[k] = wh1g[c * 33 + k];
        Wh2[k] = wh2g[c * 33 + k];
        Wv1[k] = wv1g[c * 33 + k];
        Wv2[k] = wv2g[c * 33 + k];
    }

    // lane constants for nearest-upsample: float4 slots m = j, j+64, j+128
    int g0s[3], rs[3];
#pragma unroll
    for (int u = 0; u < 3; ++u) {
        int m = j + 64 * u;
        int c4 = m % 48;
        int jj = 4 * c4;
        g0s[u] = jj / 3;
        rs[u] = jj - 3 * (jj / 3);
    }

    float racc[13];
#pragma unroll
    for (int k = 0; k < 13; ++k) racc[k] = 0.f;

    const float4* xp4 = (const float4*)xp;
    float4* op4 = (float4*)(out + (size_t)plane * 36864);

#pragma unroll
    for (int tt = 0; tt < 20; ++tt) {
        const int t = t0 + tt;
        if (t >= 0 && t < 64) {            // wave-uniform
            float w_[13];
#pragma unroll
            for (int d = 0; d < 13; ++d) w_[d] = T[t * 80 + j + d];
            // h1 + h2
#pragma unroll
            for (int p = 0; p < 11; ++p) {
                racc[(tt + 11 - p) % 13] +=
                    Wh1[p * 3 + 0] * w_[5] + Wh1[p * 3 + 1] * w_[6] +
                    Wh1[p * 3 + 2] * w_[7] +
                    Wh2[p * 3 + 0] * w_[10 - p] +
                    Wh2[p * 3 + 1] * w_[11 - p] +
                    Wh2[p * 3 + 2] * w_[12 - p];
            }
            // w1 + w2
#pragma unroll
            for (int p = 0; p < 3; ++p) {
#pragma unroll
                for (int q = 0; q < 11; ++q) {
                    racc[(tt + 7 - p) % 13] += Wv1[p * 11 + q] * w_[q + 1];
                    racc[(tt + 2 - p + q) % 13] += Wv2[p * 11 + q] * w_[q + 1];
                }
            }
        }
        if (tt >= 12) {
            const int i = ib + tt - 12;
            const int fb = i * 144;        // float4 base of out rows 3i..3i+2
            // x loads early (independent of gate; L3-hot from phase A)
            float4 xv0 = xp4[fb + j];
            float4 xv1 = xp4[fb + 64 + j];
            float4 xv2;
            if (j < 16) xv2 = xp4[fb + 128 + j];
            // finish gate value for (row i, col j) — one value per lane
            float z = racc[tt % 13] * inv + bias;
            float g = 1.f / (1.f + __expf(-z));
            // upsample gather via shuffles (all lanes active here)
            float ga0 = __shfl(g, g0s[0]), gb0 = __shfl(g, g0s[0] + 1);
            float ga1 = __shfl(g, g0s[1]), gb1 = __shfl(g, g0s[1] + 1);
            float ga2 = __shfl(g, g0s[2]), gb2 = __shfl(g, g0s[2] + 1);
            {
                float4 o;
                o.x = xv0.x * ga0;
                o.y = xv0.y * (rs[0] == 2 ? gb0 : ga0);
                o.z = xv0.z * (rs[0] == 0 ? ga0 : gb0);
                o.w = xv0.w * gb0;
                op4[fb + j] = o;
            }
            {
                float4 o;
                o.x = xv1.x * ga1;
                o.y = xv1.y * (rs[1] == 2 ? gb1 : ga1);
                o.z = xv1.z * (rs[1] == 0 ? ga1 : gb1);
                o.w = xv1.w * gb1;
                op4[fb + 64 + j] = o;
            }
            if (j < 16) {
                float4 o;
                o.x = xv2.x * ga2;
                o.y = xv2.y * (rs[2] == 2 ? gb2 : ga2);
                o.z = xv2.z * (rs[2] == 0 ? ga2 : gb2);
                o.w = xv2.w * gb2;
                op4[fb + 128 + j] = o;
            }
        }
        racc[tt % 13] = 0.f;
    }
}

extern "C" void kernel_launch(void* const* d_in, const int* in_sizes, int n_in,
                              void* d_out, int out_size, void* d_ws, size_t ws_size,
                              hipStream_t stream) {
    const float* x     = (const float*)d_in[0];
    const float* wh1   = (const float*)d_in[1];
    const float* wv1   = (const float*)d_in[2];
    const float* wh2   = (const float*)d_in[3];
    const float* wv2   = (const float*)d_in[4];
    const float* gamma = (const float*)d_in[5];
    const float* beta  = (const float*)d_in[6];
    const float* mean  = (const float*)d_in[7];
    const float* var   = (const float*)d_in[8];
    float* out  = (float*)d_out;

    mra_fused<<<1024, 512, 0, stream>>>(x, wh1, wv1, wh2, wv2,
                                        gamma, beta, mean, var, out);
}

// Round 7
// 297.554 us; speedup vs baseline: 1.0122x; 1.0122x over previous
//
#include <hip/hip_runtime.h>
#include <math.h>

// ---------------------------------------------------------------------------
// Fully fused MRA, single-pass stencil with exact tap guards: one block =
// one plane, 512 threads = 8 waves, each wave owns an 8-row strip of the
// 64x64 pooled tile. ONE barrier. LDS = T(64x80) = 20480 B.
//
// Phase A (per-wave, barrier-free): maxpool3x3(s1,p1) + blurpool([1,3,3,1]^2
//   /64, s3, reflect(1,2)) directly from global x with a rolling 6x6 register
//   window. Row/col clamp == replicate (exact for max windows); blur reflect
//   at i=0/j=0 via 1-op selects. Writes cols 6..69 of own T strip; border
//   cols stay zero = stencil zero-pad.
// [barrier]
// Phase B+C: all four stencils in ONE 20-iteration t-loop. Since a wave emits
//   only 8 outputs (< 13 = max row extent), each output k = i-ib gets a
//   DEDICATED accumulator acc[k]; every tap has a compile-time guard
//   (h1/h2: k = tt-1-p; w1: k = tt-5-p; w2: k = tt-10-p+q; keep iff 0<=k<8),
//   so the unrolled code contains exactly 132 FMA per output — no dead taps,
//   no rotating-slot zeroing, and unused w_[d] LDS reads are DCE'd per tt.
//   At tt>=12: BN + sigmoid -> per-lane gate g; nearest-upsample gather via
//   6 __shfl; stream out rows 3i..3i+2 (x loads L3-hot from phase A).
// ---------------------------------------------------------------------------
__global__ __launch_bounds__(512, 8) void mra_fused(
    const float* __restrict__ x,
    const float* __restrict__ wh1g, const float* __restrict__ wv1g,
    const float* __restrict__ wh2g, const float* __restrict__ wv2g,
    const float* __restrict__ gamma, const float* __restrict__ beta,
    const float* __restrict__ mean, const float* __restrict__ var,
    float* __restrict__ out) {
    const int plane = blockIdx.x;          // 0..1023
    const int c = plane & 63;
    __shared__ float T[64 * 80];           // pooled tile, cols 6..69 live

    const int j = threadIdx.x & 63;        // lane = column
    const int il = threadIdx.x >> 6;       // wave id 0..7
    const int ib = il * 8;                 // strip base row

    // zero own 8-row strip of T (wave-local)
    {
        float4 z4 = make_float4(0.f, 0.f, 0.f, 0.f);
        float4* t4 = (float4*)(T + ib * 80);   // 8*80 floats = 160 float4
#pragma unroll
        for (int u = 0; u < 3; ++u) {
            int idx = u * 64 + j;
            if (idx < 160) t4[idx] = z4;
        }
    }

    const float* xp = x + (size_t)plane * 36864;

    // ---- Phase A: per-wave pooling into own strip of T ----
    {
        int colk[6];
#pragma unroll
        for (int k = 0; k < 6; ++k)
            colk[k] = min(max(3 * j - 2 + k, 0), 191);

        float rw[6][6];
#pragma unroll
        for (int s = 0; s < 6; ++s) {
            const float* rp = xp + (size_t)min(max(3 * ib - 2 + s, 0), 191) * 192;
#pragma unroll
            for (int k = 0; k < 6; ++k) rw[s][k] = rp[colk[k]];
        }

#define POOL_EMIT(I, S0, S1, S2, S3, S4, S5)                              \
        {                                                                 \
            float cbv[4];                                                 \
            {                                                             \
                float vmu[4][6];                                          \
                _Pragma("unroll") for (int k = 0; k < 6; ++k) {           \
                    float p0 = rw[S0][k], p1 = rw[S1][k], p2 = rw[S2][k]; \
                    float p3 = rw[S3][k], p4 = rw[S4][k], p5 = rw[S5][k]; \
                    float q1 = fmaxf(p1, p2), q2 = fmaxf(p2, p3);         \
                    float q3 = fmaxf(p3, p4), q4 = fmaxf(p4, p5);         \
                    vmu[0][k] = fmaxf(p0, q1);                            \
                    vmu[1][k] = fmaxf(p1, q2);                            \
                    vmu[2][k] = fmaxf(p2, q3);                            \
                    vmu[3][k] = fmaxf(p3, q4);                            \
                }                                                         \
                _Pragma("unroll") for (int u = 0; u < 4; ++u) {           \
                    float g1 = fmaxf(vmu[u][1], vmu[u][2]);               \
                    float g2 = fmaxf(vmu[u][2], vmu[u][3]);               \
                    float g3 = fmaxf(vmu[u][3], vmu[u][4]);               \
                    float g4 = fmaxf(vmu[u][4], vmu[u][5]);               \
                    float h0 = fmaxf(vmu[u][0], g1);                      \
                    float h1 = fmaxf(vmu[u][1], g2);                      \
                    float h2 = fmaxf(vmu[u][2], g3);                      \
                    float h3 = fmaxf(vmu[u][3], g4);                      \
                    float ha = (j == 0) ? h2 : h0;   /* col reflect */    \
                    cbv[u] = ha + 3.f * h1 + 3.f * h2 + h3;               \
                }                                                         \
            }                                                             \
            float c0 = ((I) == 0) ? cbv[2] : cbv[0]; /* row reflect */    \
            float accv = c0 + 3.f * cbv[1] + 3.f * cbv[2] + cbv[3];       \
            T[(I) * 80 + 6 + j] = accv * (1.f / 64.f);                    \
        }

#define LOAD3(BR, S0, S1, S2)                                             \
        {                                                                 \
            const float* rp0 = xp + (size_t)min((BR), 191) * 192;         \
            const float* rp1 = xp + (size_t)min((BR) + 1, 191) * 192;     \
            const float* rp2 = xp + (size_t)min((BR) + 2, 191) * 192;     \
            _Pragma("unroll") for (int k = 0; k < 6; ++k) {               \
                rw[S0][k] = rp0[colk[k]];                                 \
                rw[S1][k] = rp1[colk[k]];                                 \
                rw[S2][k] = rp2[colk[k]];                                 \
            }                                                             \
        }

#pragma unroll 1
        for (int ii = 0; ii < 8; ii += 2) {
            const int i = ib + ii;
            POOL_EMIT(i, 0, 1, 2, 3, 4, 5);
            LOAD3(3 * i + 4, 0, 1, 2);
            POOL_EMIT(i + 1, 3, 4, 5, 0, 1, 2);
            if (ii < 6) LOAD3(3 * i + 7, 3, 4, 5);
        }
#undef POOL_EMIT
#undef LOAD3
    }
    __syncthreads();   // the ONLY barrier: T complete incl. halo strips

    // ---- Phase B+C: guarded single-pass stencil + BN/sigmoid + output ----
    const float inv = gamma[c] * rsqrtf(var[c] + 1e-5f);
    const float bias = beta[c] - mean[c] * inv;
    const int t0 = ib - 6;

    float Wh1[33], Wh2[33], Wv1[33], Wv2[33];
#pragma unroll
    for (int k = 0; k < 33; ++k) {
        Wh1[k] = wh1g[c * 33 + k];
        Wh2[k] = wh2g[c * 33 + k];
        Wv1[k] = wv1g[c * 33 + k];
        Wv2[k] = wv2g[c * 33 + k];
    }

    // lane constants for nearest-upsample: float4 slots m = j, j+64, j+128
    int g0s[3], rs[3];
#pragma unroll
    for (int u = 0; u < 3; ++u) {
        int m = j + 64 * u;
        int c4 = m % 48;
        int jj = 4 * c4;
        g0s[u] = jj / 3;
        rs[u] = jj - 3 * (jj / 3);
    }

    float acc[8];
#pragma unroll
    for (int k = 0; k < 8; ++k) acc[k] = 0.f;

    const float4* xp4 = (const float4*)xp;
    float4* op4 = (float4*)(out + (size_t)plane * 36864);

#pragma unroll
    for (int tt = 0; tt < 20; ++tt) {
        const int t = t0 + tt;
        if (t >= 0 && t < 64) {            // wave-uniform (waves 0 and 7 clip)
            float w_[13];
#pragma unroll
            for (int d = 0; d < 13; ++d) w_[d] = T[t * 80 + j + d];
            // h1 + h2: output k = tt - 1 - p  (p = row tap 0..10)
#pragma unroll
            for (int k = 0; k < 8; ++k) {
                const int p = tt - 1 - k;
                if (p >= 0 && p < 11) {    // compile-time after unroll
                    acc[k] += Wh1[p * 3 + 0] * w_[5] + Wh1[p * 3 + 1] * w_[6] +
                              Wh1[p * 3 + 2] * w_[7] +
                              Wh2[p * 3 + 0] * w_[10 - p] +
                              Wh2[p * 3 + 1] * w_[11 - p] +
                              Wh2[p * 3 + 2] * w_[12 - p];
                }
            }
            // w1: output k = tt - 5 - p  (p = 0..2)
#pragma unroll
            for (int p = 0; p < 3; ++p) {
                const int k = tt - 5 - p;
                if (k >= 0 && k < 8) {
#pragma unroll
                    for (int q = 0; q < 11; ++q)
                        acc[k] += Wv1[p * 11 + q] * w_[q + 1];
                }
            }
            // w2: output k = tt - 10 - p + q
#pragma unroll
            for (int p = 0; p < 3; ++p) {
#pragma unroll
                for (int q = 0; q < 11; ++q) {
                    const int k = tt - 10 - p + q;
                    if (k >= 0 && k < 8)
                        acc[k] += Wv2[p * 11 + q] * w_[q + 1];
                }
            }
        }
        if (tt >= 12) {
            const int k = tt - 12;
            const int i = ib + k;
            const int fb = i * 144;        // float4 base of out rows 3i..3i+2
            // x loads early (independent of gate; L3-hot from phase A)
            float4 xv0 = xp4[fb + j];
            float4 xv1 = xp4[fb + 64 + j];
            float4 xv2;
            if (j < 16) xv2 = xp4[fb + 128 + j];
            // finish gate value for (row i, col j) — one value per lane
            float z = acc[k] * inv + bias;
            float g = 1.f / (1.f + __expf(-z));
            // upsample gather via shuffles (all lanes active here)
            float ga0 = __shfl(g, g0s[0]), gb0 = __shfl(g, g0s[0] + 1);
            float ga1 = __shfl(g, g0s[1]), gb1 = __shfl(g, g0s[1] + 1);
            float ga2 = __shfl(g, g0s[2]), gb2 = __shfl(g, g0s[2] + 1);
            {
                float4 o;
                o.x = xv0.x * ga0;
                o.y = xv0.y * (rs[0] == 2 ? gb0 : ga0);
                o.z = xv0.z * (rs[0] == 0 ? ga0 : gb0);
                o.w = xv0.w * gb0;
                op4[fb + j] = o;
            }
            {
                float4 o;
                o.x = xv1.x * ga1;
                o.y = xv1.y * (rs[1] == 2 ? gb1 : ga1);
                o.z = xv1.z * (rs[1] == 0 ? ga1 : gb1);
                o.w = xv1.w * gb1;
                op4[fb + 64 + j] = o;
            }
            if (j < 16) {
                float4 o;
                o.x = xv2.x * ga2;
                o.y = xv2.y * (rs[2] == 2 ? gb2 : ga2);
                o.z = xv2.z * (rs[2] == 0 ? ga2 : gb2);
                o.w = xv2.w * gb2;
                op4[fb + 128 + j] = o;
            }
        }
    }
}

extern "C" void kernel_launch(void* const* d_in, const int* in_sizes, int n_in,
                              void* d_out, int out_size, void* d_ws, size_t ws_size,
                              hipStream_t stream) {
    const float* x     = (const float*)d_in[0];
    const float* wh1   = (const float*)d_in[1];
    const float* wv1   = (const float*)d_in[2];
    const float* wh2   = (const float*)d_in[3];
    const float* wv2   = (const float*)d_in[4];
    const float* gamma = (const float*)d_in[5];
    const float* beta  = (const float*)d_in[6];
    const float* mean  = (const float*)d_in[7];
    const float* var   = (const float*)d_in[8];
    float* out  = (float*)d_out;

    mra_fused<<<1024, 512, 0, stream>>>(x, wh1, wv1, wh2, wv2,
                                        gamma, beta, mean, var, out);
}